// Round 4
// baseline (809.913 us; speedup 1.0000x reference)
//
#include <hip/hip_runtime.h>
#include <hip/hip_bf16.h>

typedef __attribute__((ext_vector_type(8))) __bf16 bf16x8;
typedef __attribute__((ext_vector_type(4))) float floatx4;

constexpr int N_TOK = 4096;   // B*T
constexpr int DDIM  = 1024;
constexpr int FDIM  = 4096;
constexpr int NEXP  = 8;
constexpr int NSLOT = 2 * N_TOK; // 8192 assignments (top-2)
constexpr int BM_T  = 256;       // M tile
constexpr int MAXT  = NSLOT / BM_T + NEXP - 1; // 39 max M-tiles at BM=256

static __device__ __forceinline__ unsigned short f2bf(float f) {
    union { __hip_bfloat16 h; unsigned short u; } v;
    v.h = __float2bfloat16(f);
    return v.u;
}

// async 16B global->LDS DMA. LDS dest = wave-uniform base + lane*16 (m104/m108).
static __device__ __forceinline__ void gl2lds16(const unsigned short* g, unsigned short* l) {
    __builtin_amdgcn_global_load_lds(
        (__attribute__((address_space(1))) void*)g,
        (__attribute__((address_space(3))) void*)l,
        16, 0, 0);
}

// ---------------- merged prep: router (blocks 0..1023) + W1/W2 cast (rest) ----------------
// Independent work items fused into one launch so the cast's HBM streaming overlaps the
// router's compute. counts[] is zeroed by hipMemsetAsync before this kernel.
__global__ void prep_kernel(const float* __restrict__ x, const float* __restrict__ Wr,
                            const float* __restrict__ W1, const float* __restrict__ W2,
                            unsigned short* __restrict__ xb,
                            unsigned short* __restrict__ w1b, unsigned short* __restrict__ w2b,
                            int* __restrict__ te, float* __restrict__ tw,
                            int* __restrict__ counts) {
    constexpr int RBLK = N_TOK / 4;                  // 1024 router blocks
    __shared__ float wr[NEXP * DDIM];                // 32 KB (router branch only)
    const int tid = threadIdx.x;
    if (blockIdx.x >= RBLK) {
        // ---- castW branch ----
        constexpr int HALF = NEXP * FDIM * DDIM / 4; // float4 groups per tensor
        int i = (blockIdx.x - RBLK) * 256 + tid;
        const float* s; unsigned short* d; int j;
        if (i < HALF) { s = W1; d = w1b; j = i; }
        else          { s = W2; d = w2b; j = i - HALF; }
        float4 v = *(const float4*)(s + (size_t)j * 4);
        ushort4 o;
        o.x = f2bf(v.x); o.y = f2bf(v.y); o.z = f2bf(v.z); o.w = f2bf(v.w);
        *(ushort4*)(d + (size_t)j * 4) = o;
        return;
    }
    // ---- router branch ----
    for (int i = tid; i < NEXP * DDIM; i += 256) wr[i] = Wr[i];
    __syncthreads();
    const int wave = tid >> 6, lane = tid & 63;
    const int t = blockIdx.x * 4 + wave;

    float xr[16];
    const float* xp = x + (size_t)t * DDIM;
    #pragma unroll
    for (int i = 0; i < 16; i++) xr[i] = xp[lane + 64 * i];

    unsigned short* xbp = xb + (size_t)t * DDIM;     // fused x -> bf16 cast
    #pragma unroll
    for (int i = 0; i < 16; i++) xbp[lane + 64 * i] = f2bf(xr[i]);

    float logit[NEXP];
    #pragma unroll
    for (int e = 0; e < NEXP; e++) {
        float s = 0.f;
        #pragma unroll
        for (int i = 0; i < 16; i++) s += xr[i] * wr[e * DDIM + lane + 64 * i];
        #pragma unroll
        for (int off = 32; off > 0; off >>= 1) s += __shfl_xor(s, off, 64);
        logit[e] = s;
    }
    if (lane == 0) {
        int i0 = 0; float l0 = logit[0];
        #pragma unroll
        for (int e = 1; e < NEXP; e++) if (logit[e] > l0) { l0 = logit[e]; i0 = e; }
        int i1 = -1; float l1 = -3.0e38f;
        #pragma unroll
        for (int e = 0; e < NEXP; e++) if (e != i0 && logit[e] > l1) { l1 = logit[e]; i1 = e; }
        float p1 = expf(l1 - l0);
        float w0 = 1.f / (1.f + p1);
        float w1 = p1 * w0;
        te[t * 2] = i0; te[t * 2 + 1] = i1;
        tw[t * 2] = w0; tw[t * 2 + 1] = w1;
        atomicAdd(&counts[i0], 1);
        atomicAdd(&counts[i1], 1);
    }
}

// ---------------- fused scan + tile table + scatter (single block) ----------------
__global__ void scan_scatter_kernel(const int* __restrict__ counts,
                                    const int* __restrict__ te, const float* __restrict__ tw,
                                    int* __restrict__ offsets, int* __restrict__ tile_em,
                                    int* __restrict__ ntile,
                                    int* __restrict__ rowid, float* __restrict__ gate,
                                    int* __restrict__ tok2slot) {
    __shared__ int soff[NEXP];
    __shared__ int scur[NEXP];
    const int tid = threadIdx.x;
    if (tid == 0) {
        int acc = 0, nt = 0;
        for (int e = 0; e < NEXP; e++) {
            offsets[e] = acc; soff[e] = acc;
            for (int m0 = 0; m0 < counts[e]; m0 += BM_T)
                tile_em[nt++] = (e << 16) | (m0 >> 8);
            acc += counts[e];
        }
        offsets[NEXP] = acc;
        ntile[0] = nt;
        for (int i = nt; i < MAXT; i++) tile_em[i] = 0;
    }
    if (tid < NEXP) scur[tid] = 0;
    __syncthreads();
    for (int t = tid; t < N_TOK; t += 256) {
        #pragma unroll
        for (int k = 0; k < 2; k++) {
            int e = te[t * 2 + k];
            int pos = atomicAdd(&scur[e], 1);
            int slot = soff[e] + pos;
            rowid[slot] = t;
            gate[slot] = tw[t * 2 + k];
            tok2slot[t * 2 + k] = slot;
        }
    }
}

// ---------------- grouped GEMM: 256x256 BK=64, 8 waves, 8-phase counted-vmcnt ----------------
// m201/m248 design point. 4 phases per K-tile; stage order A-mh0/B-nh0/B-nh1/A-mh1.
// vmcnt ledger (per wave, 2 loads/phase): entering (t,0) the (t-1,3) wait has retired
// stages <=(t-1,1) = exactly {A-mh0,B-nh0} that phase 0 reads; (t,0)'s vmcnt(4) retires
// (t-1,2)=B-nh1 before (t,1) reads it; (t,1)'s retires (t-1,3)=A-mh1 before (t,2).
// s_barrier after each wait globalizes the confirmation (all waves stage all halves).
// WAR: buf p^1 (stage target during tile t) was last read in tile t-1; every phase does
// lgkmcnt(0) BEFORE its barrier, so all reads complete before the next stage can issue.
// Full 8-way XOR swizzle (16B-chunk ^ row&7 at 128 B rows) on source AND read -> b128
// reads conflict-free (consecutive lane octets hit all 8 chunk slots).
template <bool UP, int KS>
__global__ __launch_bounds__(512, 2)
void ffn_gemm(const unsigned short* __restrict__ A,
              const unsigned short* __restrict__ Wb,
              unsigned short* __restrict__ Hout,
              float* __restrict__ Y,
              const int* __restrict__ rowid,
              const float* __restrict__ gate,
              const int* __restrict__ offsets,
              const int* __restrict__ tile_em,
              const int* __restrict__ ntile) {
    constexpr int BM = 256, BN = 256, BK = 64;
    constexpr int NOUT = UP ? FDIM : DDIM;
    constexpr int KDIM = UP ? DDIM : FDIM;
    constexpr int NN   = NOUT / BN;                  // 16 / 4
    constexpr int KLEN = UP ? DDIM : (FDIM / KS);    // 1024 / (4096/KS)
    constexpr int KT   = KLEN / BK;                  // 16 / ...
    constexpr int AST  = BM * BK;                    // 16384 shorts = 32 KB per buffer

    // bijective XCD-chunked swizzle (m204)
    const int nwg = NN * MAXT * (UP ? 1 : KS);       // == gridDim.x
    const int orig = blockIdx.x;
    const int xcd = orig & 7, idx = orig >> 3;
    const int qq = nwg >> 3, rr8 = nwg & 7;
    const int id = (xcd < rr8 ? xcd * (qq + 1) : rr8 * (qq + 1) + (xcd - rr8) * qq) + idx;

    const int n0 = (id % NN) * BN;                   // n fastest: neighbors share A tile
    const int bt = (id / NN) % MAXT;
    const int ks = UP ? 0 : (id / (NN * MAXT));
    if (bt >= ntile[0]) return;
    const int em = tile_em[bt];
    const int e  = em >> 16;
    const int m0 = (em & 0xffff) << 8;
    const int seg = offsets[e];
    const int cnt = offsets[e + 1] - seg;
    const int kbase = ks * KLEN;

    __shared__ __align__(16) unsigned short As[2 * AST]; // 64 KB
    __shared__ __align__(16) unsigned short Bs[2 * AST]; // 64 KB

    const int tid  = threadIdx.x;
    const int lane = tid & 63;
    const int wave = tid >> 6;
    const int lrow = lane >> 3;                      // 0..7: row within 8-row DMA granule
    const int chunk = lane & 7;                      // 16B chunk within 128B row
    const int scoff = (chunk ^ lrow) * 8;            // inverse-swizzled SOURCE col (shorts)
    const int h = wave >> 2;                         // stage-half assignment (0/1)

    // stage pointers: pp=0 -> phase0 (A-mh0) / phase1 (B-nh0); pp=1 -> phase3 (A-mh1) / phase2 (B-nh1)
    const unsigned short* gA[2][2]; int dA[2][2];
    #pragma unroll
    for (int pp = 0; pp < 2; pp++) {
        #pragma unroll
        for (int j = 0; j < 2; j++) {
            int o = pp * 8 + (wave & 3) * 2 + j;     // A octets: mh0 -> o0-7, mh1 -> o8-15
            int rl = h * 128 + o * 8 + lrow;
            dA[pp][j] = (h * 128 + o * 8) * BK + lane * 8;
            int slot = seg + m0 + rl;
            if (slot >= NSLOT) slot = NSLOT - 1;     // clamp; write-guarded later
            if (UP) { int trow = rowid[slot]; gA[pp][j] = A + (size_t)trow * KDIM + kbase + scoff; }
            else    { gA[pp][j] = A + (size_t)slot * KDIM + kbase + scoff; }
        }
    }
    const unsigned short* gB[2][2]; int dB[2][2];
    #pragma unroll
    for (int pp = 0; pp < 2; pp++) {
        #pragma unroll
        for (int j = 0; j < 2; j++) {
            int o = ((wave >> 1) & 1) * 8 + pp * 4 + (wave & 1) * 2 + j; // nh0: o{0-3,8-11}; nh1: +4
            int rl = h * 128 + o * 8 + lrow;
            dB[pp][j] = (h * 128 + o * 8) * BK + lane * 8;
            gB[pp][j] = Wb + ((size_t)e * NOUT + n0 + rl) * KDIM + kbase + scoff;
        }
    }

    auto stA = [&](int pp, int b) {
        gl2lds16(gA[pp][0], &As[b * AST + dA[pp][0]]); gA[pp][0] += BK;
        gl2lds16(gA[pp][1], &As[b * AST + dA[pp][1]]); gA[pp][1] += BK;
    };
    auto stB = [&](int pp, int b) {
        gl2lds16(gB[pp][0], &Bs[b * AST + dB[pp][0]]); gB[pp][0] += BK;
        gl2lds16(gB[pp][1], &Bs[b * AST + dB[pp][1]]); gB[pp][1] += BK;
    };

    const int frow = lane & 15;
    const int quad = lane >> 4;
    const int fx   = frow & 7;                       // read-side swizzle row bits
    const int wm = (wave >> 2) * 128;                // 2 M-waves
    const int wn = (wave & 3) * 64;                  // 4 N-waves

    floatx4 acc[8][4];
    #pragma unroll
    for (int i = 0; i < 8; i++)
        #pragma unroll
        for (int j = 0; j < 4; j++)
            acc[i][j] = (floatx4){0.f, 0.f, 0.f, 0.f};

    // prologue: stage K-tile 0 fully into buf 0, drain once
    stA(0, 0); stB(0, 0); stB(1, 0); stA(1, 0);
    asm volatile("s_waitcnt vmcnt(0)" ::: "memory");
    __builtin_amdgcn_s_barrier();

    for (int t = 0; t < KT; ++t) {
        const int pb = t & 1;
        const bool more = (t + 1 < KT);
        #pragma unroll
        for (int ph = 0; ph < 4; ++ph) {
            if (more) {                              // stage one half of K-tile t+1
                if      (ph == 0) stA(0, pb ^ 1);
                else if (ph == 1) stB(0, pb ^ 1);
                else if (ph == 2) stB(1, pb ^ 1);
                else              stA(1, pb ^ 1);
            }
            const int mh = ph >> 1, nh = ph & 1;
            bf16x8 av[4][2], bv[2][2];
            #pragma unroll
            for (int i = 0; i < 4; i++)
                #pragma unroll
                for (int kk = 0; kk < 2; kk++)
                    av[i][kk] = *(const bf16x8*)&As[pb * AST + (wm + mh * 64 + i * 16 + frow) * BK
                                                   + (((kk * 4 + quad) ^ fx) * 8)];
            #pragma unroll
            for (int j = 0; j < 2; j++)
                #pragma unroll
                for (int kk = 0; kk < 2; kk++)
                    bv[j][kk] = *(const bf16x8*)&Bs[pb * AST + (wn + nh * 32 + j * 16 + frow) * BK
                                                   + (((kk * 4 + quad) ^ fx) * 8)];
            if (more)        asm volatile("s_waitcnt vmcnt(4) lgkmcnt(0)" ::: "memory");
            else if (ph == 0) asm volatile("s_waitcnt vmcnt(2) lgkmcnt(0)" ::: "memory");
            else              asm volatile("s_waitcnt vmcnt(0) lgkmcnt(0)" ::: "memory");
            __builtin_amdgcn_s_barrier();
            __builtin_amdgcn_sched_barrier(0);
            __builtin_amdgcn_s_setprio(1);
            #pragma unroll
            for (int i = 0; i < 4; i++)
                #pragma unroll
                for (int j = 0; j < 2; j++) {
                    acc[mh * 4 + i][nh * 2 + j] =
                        __builtin_amdgcn_mfma_f32_16x16x32_bf16(av[i][0], bv[j][0],
                                                                acc[mh * 4 + i][nh * 2 + j], 0, 0, 0);
                    acc[mh * 4 + i][nh * 2 + j] =
                        __builtin_amdgcn_mfma_f32_16x16x32_bf16(av[i][1], bv[j][1],
                                                                acc[mh * 4 + i][nh * 2 + j], 0, 0, 0);
                }
            __builtin_amdgcn_s_setprio(0);
        }
    }

    // epilogue: C/D layout col=lane&15, row=quad*4+reg (m89/m91-verified)
    #pragma unroll
    for (int mt = 0; mt < 8; mt++) {
        #pragma unroll
        for (int rg = 0; rg < 4; rg++) {
            int mloc = m0 + wm + mt * 16 + quad * 4 + rg;
            if (mloc >= cnt) continue;               // write-guard
            int slot = seg + mloc;
            if (UP) {
                #pragma unroll
                for (int nt = 0; nt < 4; nt++) {
                    int n = n0 + wn + nt * 16 + frow;
                    float v = acc[mt][nt][rg];
                    float g = 0.5f * v * (1.0f + erff(v * 0.70710678118654752f)); // exact gelu
                    Hout[(size_t)slot * FDIM + n] = f2bf(g);
                }
            } else {
                float gw = gate[slot];
                #pragma unroll
                for (int nt = 0; nt < 4; nt++) {
                    int n = n0 + wn + nt * 16 + frow;
                    Y[((size_t)ks * NSLOT + slot) * DDIM + n] = gw * acc[mt][nt][rg];
                }
            }
        }
    }
}

// ---------------- combine: out[t] = sum over ks slabs of Y[slot0]+Y[slot1] ----------------
__global__ void combine_kernel(const float* __restrict__ Y, const int* __restrict__ tok2slot,
                               float* __restrict__ out, int nks) {
    int idx = blockIdx.x * 256 + threadIdx.x;
    int t = idx >> 8;
    int c = (idx & 255) * 4;
    int s0 = tok2slot[t * 2], s1 = tok2slot[t * 2 + 1];
    float4 r = make_float4(0.f, 0.f, 0.f, 0.f);
    for (int ks = 0; ks < nks; ks++) {
        float4 a = *(const float4*)(Y + ((size_t)ks * NSLOT + s0) * DDIM + c);
        float4 b = *(const float4*)(Y + ((size_t)ks * NSLOT + s1) * DDIM + c);
        r.x += a.x + b.x; r.y += a.y + b.y; r.z += a.z + b.z; r.w += a.w + b.w;
    }
    *(float4*)(out + (size_t)t * DDIM + c) = r;
}

extern "C" void kernel_launch(void* const* d_in, const int* in_sizes, int n_in,
                              void* d_out, int out_size, void* d_ws, size_t ws_size,
                              hipStream_t stream) {
    const float* x  = (const float*)d_in[0];
    const float* Wr = (const float*)d_in[1];
    const float* W1 = (const float*)d_in[2];
    const float* W2 = (const float*)d_in[3];
    float* out = (float*)d_out;

    // workspace plan; DOWN K-split = 4 if it fits (grid packing), else 2
    auto plan = [&](int nks, size_t& total) {
        size_t off = 0;
        auto sz = [&](size_t bytes) { size_t p = off; off = (off + bytes + 255) & ~(size_t)255; return p; };
        sz((size_t)N_TOK * DDIM * 2);                // xb
        sz((size_t)NSLOT * FDIM * 2);                // H
        sz((size_t)nks * NSLOT * DDIM * 4);          // Yb
        sz(NSLOT * 4); sz(NSLOT * 4); sz(NSLOT * 4); sz(NSLOT * 4); sz(NSLOT * 4);
        sz(64); sz(64); sz(MAXT * 4); sz(64);
        sz((size_t)NEXP * FDIM * DDIM * 2);          // w1b
        sz((size_t)NEXP * DDIM * FDIM * 2);          // w2b
        total = off;
    };
    size_t need4, need2;
    plan(4, need4); plan(2, need2);
    const int nks = (need4 <= ws_size) ? 4 : 2;

    char* ws = (char*)d_ws;
    size_t off = 0;
    auto alloc = [&](size_t bytes) -> char* {
        char* p = ws + off;
        off = (off + bytes + 255) & ~(size_t)255;
        return p;
    };
    unsigned short* xb   = (unsigned short*)alloc((size_t)N_TOK * DDIM * 2);
    unsigned short* H    = (unsigned short*)alloc((size_t)NSLOT * FDIM * 2);
    float* Yb      = (float*)alloc((size_t)nks * NSLOT * DDIM * 4);
    int*   rowid   = (int*)alloc(NSLOT * 4);
    float* gatew   = (float*)alloc(NSLOT * 4);
    int*   te      = (int*)alloc(NSLOT * 4);
    float* tw      = (float*)alloc(NSLOT * 4);
    int*   t2s     = (int*)alloc(NSLOT * 4);
    int*   counts  = (int*)alloc(64);
    int*   offsets = (int*)alloc(64);
    int*   tile_em = (int*)alloc(MAXT * 4);
    int*   ntile   = (int*)alloc(64);
    unsigned short* w1b = (unsigned short*)alloc((size_t)NEXP * FDIM * DDIM * 2);
    unsigned short* w2b = (unsigned short*)alloc((size_t)NEXP * DDIM * FDIM * 2);
    (void)ws_size;

    constexpr int RBLK = N_TOK / 4;                            // 1024 router blocks
    constexpr int CBLK = 2 * NEXP * FDIM * DDIM / 4 / 256;     // 65536 cast blocks
    constexpr int GRID_UP = (FDIM / 256) * MAXT;               // 624

    hipMemsetAsync(counts, 0, NEXP * sizeof(int), stream);
    prep_kernel<<<RBLK + CBLK, 256, 0, stream>>>(x, Wr, W1, W2, xb, w1b, w2b, te, tw, counts);
    scan_scatter_kernel<<<1, 256, 0, stream>>>(counts, te, tw, offsets, tile_em, ntile,
                                               rowid, gatew, t2s);
    ffn_gemm<true, 1><<<GRID_UP, 512, 0, stream>>>(xb, w1b, H, Yb, rowid, gatew,
                                                   offsets, tile_em, ntile);
    if (nks == 4) {
        ffn_gemm<false, 4><<<(DDIM / 256) * MAXT * 4, 512, 0, stream>>>(H, w2b, H, Yb, rowid, gatew,
                                                                        offsets, tile_em, ntile);
    } else {
        ffn_gemm<false, 2><<<(DDIM / 256) * MAXT * 2, 512, 0, stream>>>(H, w2b, H, Yb, rowid, gatew,
                                                                        offsets, tile_em, ntile);
    }
    combine_kernel<<<N_TOK, 256, 0, stream>>>(Yb, t2s, out, nks);
}